// Round 16
// baseline (175.853 us; speedup 1.0000x reference)
//
#include <hip/hip_runtime.h>
#include <hip/hip_bf16.h>
#include <stdint.h>

typedef unsigned short u16;
typedef __attribute__((ext_vector_type(8))) short short8;
typedef __attribute__((ext_vector_type(4))) float f32x4;
typedef __attribute__((ext_vector_type(16))) float f32x16;

#define GLOBAL_AS __attribute__((address_space(1)))
#define LDS_AS __attribute__((address_space(3)))

#define BB 4
#define NSEQ 2048
#define DIN 768
#define DOUT 768
#define NH 12
#define HD 64
#define MROWS (BB*NSEQ)   // 8192

static __device__ __forceinline__ u16 f2bf(float f) {
  union { float f; uint32_t u; } v; v.f = f;
  uint32_t r = (v.u + 0x7fffu + ((v.u >> 16) & 1u)) >> 16;
  return (u16)r;
}
static __device__ __forceinline__ uint32_t pack2b(float lo, float hi) {
  union { __hip_bfloat162 h; uint32_t u; } cv;
  cv.h.x = __float2bfloat16(lo);
  cv.h.y = __float2bfloat16(hi);
  return cv.u;
}

// ---------------- convert v2 (unchanged) -----------------------------------
__global__ __launch_bounds__(256) void convert2_k(const float* __restrict__ x,
                          const float* __restrict__ Wq, const float* __restrict__ Wk,
                          const float* __restrict__ Wv, const float* __restrict__ Wo,
                          u16* __restrict__ xb, u16* __restrict__ WqT,
                          u16* __restrict__ WkT, u16* __restrict__ WvT,
                          u16* __restrict__ WoT) {
  int tid = threadIdx.x;
  if (blockIdx.x < 576) {
    int wi = blockIdx.x;
    int which = wi / 144, t = wi % 144;
    int tr = t / 12, tc = t % 12;          // k-tile, n-tile
    const float* src = which==0 ? Wq : which==1 ? Wk : which==2 ? Wv : Wo;
    u16* dst = which==0 ? WqT : which==1 ? WkT : which==2 ? WvT : WoT;
    __shared__ u16 lt[64][65];
    int r0 = tid >> 6, c = tid & 63;
#pragma unroll
    for (int rr=0; rr<16; rr++) {
      int row = rr*4 + r0;                 // k within tile
      lt[row][c] = f2bf(src[(size_t)(tr*64+row)*DOUT + tc*64 + c]);
    }
    __syncthreads();
#pragma unroll
    for (int rr=0; rr<16; rr++) {
      int row = rr*4 + r0;                 // n within tile
      dst[(size_t)(tc*64+row)*DIN + tr*64 + c] = lt[c][row];
    }
  } else {
    const float4* x4 = (const float4*)x;
    uint2* o4 = (uint2*)xb;
    int n4 = MROWS*DIN/4;                  // 1572864
    int i = (int)(blockIdx.x - 576) * 256 + tid;
    for (; i < n4; i += 2048*256) {
      float4 v = x4[i];
      uint2 o; o.x = pack2b(v.x, v.y); o.y = pack2b(v.z, v.w);
      o4[i] = o;
    }
  }
}

// ---------------- fused QKV GEMM v4c: 3-buffer counted-vmcnt + setprio -----
__global__ __launch_bounds__(256) void gemm_qkv_k(const u16* __restrict__ A,
                                                  const u16* __restrict__ Bt,
                                                  u16* __restrict__ Qg,
                                                  u16* __restrict__ Kgo,
                                                  u16* __restrict__ Vto) {
  const int K = DIN;
  int xcd = blockIdx.x & 7, j = blockIdx.x >> 3;   // j 0..143
  int m0 = (xcd*8 + (j & 7)) * 128;
  int nt = j >> 3;                                 // 0..17
  nt = (nt % 3) * 6 + nt / 3;                      // spread V^T columns
  int n0 = nt * 128;
  int tid = threadIdx.x;
  int lane = tid & 63, wid = tid >> 6;
  int wr = wid >> 1, wc = wid & 1;
  int g = lane >> 4, r = lane & 15;

  __shared__ __attribute__((aligned(16))) u16 sbuf[24576];  // 48KB
  // A bufs @ 0/4096/8192 ; B bufs @ 12288/16384/20480 (elements)

  auto stage = [&](int bi, int k0) {
    u16* dA = sbuf + bi*4096;
    u16* dB = sbuf + 12288 + bi*4096;
#pragma unroll
    for (int i=0;i<2;i++) {
      int ch = wid*2 + i;
      int e = ch*512 + lane*8;
      int row = e >> 5, col = e & 31;
      __builtin_amdgcn_global_load_lds(
        (GLOBAL_AS void*)(A + (size_t)(m0+row)*K + k0 + col),
        (LDS_AS void*)(&dA[ch*512]), 16, 0, 0);
      __builtin_amdgcn_global_load_lds(
        (GLOBAL_AS void*)(Bt + (size_t)(n0+row)*K + k0 + col),
        (LDS_AS void*)(&dB[ch*512]), 16, 0, 0);
    }
  };

  f32x4 acc[4][4];
#pragma unroll
  for (int i=0;i<4;i++)
#pragma unroll
    for (int jj=0;jj<4;jj++) acc[i][jj] = (f32x4){0.f,0.f,0.f,0.f};

  auto compute = [&](int bi, int k0) {
    const u16* sA = sbuf + bi*4096;
    const u16* sB = sbuf + 12288 + bi*4096;
    short8 af[4], bf[4];
#pragma unroll
    for (int f=0; f<4; f++) {
      af[f] = *(const short8*)&sA[(wr*64 + f*16 + r)*32 + g*8];
      bf[f] = *(const short8*)&sB[(wc*64 + f*16 + r)*32 + g*8];
    }
    __builtin_amdgcn_s_setprio(1);
#pragma unroll
    for (int fr=0; fr<4; fr++)
#pragma unroll
      for (int fc=0; fc<4; fc++)
        acc[fr][fc] = __builtin_amdgcn_mfma_f32_16x16x32_bf16(af[fr], bf[fc], acc[fr][fc], 0, 0, 0);
    __builtin_amdgcn_s_setprio(0);
  };

  stage(0, 0);
  stage(1, 32);
  for (int k0 = 0; k0 < K; k0 += 96) {
    asm volatile("s_waitcnt vmcnt(4)" ::: "memory");
    __builtin_amdgcn_s_barrier();
    asm volatile("" ::: "memory");
    stage(2, k0 + 64);
    compute(0, k0);

    asm volatile("s_waitcnt vmcnt(4)" ::: "memory");
    __builtin_amdgcn_s_barrier();
    asm volatile("" ::: "memory");
    { int kn = k0 + 96;  stage(0, kn < K ? kn : 0); }
    compute(1, k0 + 32);

    asm volatile("s_waitcnt vmcnt(4)" ::: "memory");
    __builtin_amdgcn_s_barrier();
    asm volatile("" ::: "memory");
    { int kn = k0 + 128; stage(1, kn < K ? kn : 32); }
    compute(2, k0 + 64);
  }
  asm volatile("s_waitcnt vmcnt(0)" ::: "memory");
  __syncthreads();   // all loads landed + all compute done before epilogue reuse

  if (n0 < 1536) {                   // Q or K path
    bool isQ = n0 < 768;
    u16* outb = isQ ? Qg : Kgo;
    int nb = isQ ? n0 : n0 - 768;
#pragma unroll
    for (int fr=0; fr<4; fr++)
#pragma unroll
      for (int fc=0; fc<4; fc++)
#pragma unroll
        for (int v=0; v<4; v++) {
          int row = m0 + wr*64 + fr*16 + g*4 + v;
          int cc  = nb + wc*64 + fc*16 + r;
          int b = row >> 11, nn = row & (NSEQ-1);
          float val = acc[fr][fc][v];
          if (isQ) val *= 0.18033688f;   // 0.125 * log2(e)
          outb[(((size_t)b*NH + (cc>>6))*NSEQ + nn)*HD + (cc&63)] = f2bf(val);
        }
  } else {                           // V^T path: single-shot LDS transpose
    int nb = n0 - 1536;
#pragma unroll
    for (int fr=0; fr<4; fr++)
#pragma unroll
      for (int fc=0; fc<4; fc++)
#pragma unroll
        for (int v=0; v<4; v++) {
          int ii = wr*64 + fr*16 + g*4 + v;
          int jj = wc*64 + fc*16 + r;
          sbuf[ii*129 + jj] = f2bf(acc[fr][fc][v]);
        }
    __syncthreads();
    int b = m0 >> 11;
#pragma unroll 1
    for (int rep=0; rep<64; rep++) {
      int flat = rep*256 + tid;      // 16384 elements
      int jj = flat >> 7, ii = flat & 127;
      int cc = nb + jj;
      int nn = (m0 + ii) & (NSEQ-1);
      Vto[(((size_t)b*NH + (cc>>6))*HD + (cc&63))*NSEQ + nn] = sbuf[ii*129 + jj];
    }
  }
}

// ---------------- final GEMM v4c: 3-buffer counted-vmcnt + setprio ---------
__global__ __launch_bounds__(256) void gemm_o_k(const u16* __restrict__ A,
                                                const u16* __restrict__ Bt,
                                                float* __restrict__ outf,
                                                const float* __restrict__ bias) {
  const int K = DIN;
  int xcd = blockIdx.x & 7, j = blockIdx.x >> 3;   // j 0..47
  int m0 = (xcd*8 + (j & 7)) * 128;
  int n0 = (j >> 3) * 128;                         // 0..5
  int tid = threadIdx.x;
  int lane = tid & 63, wid = tid >> 6;
  int wr = wid >> 1, wc = wid & 1;
  int g = lane >> 4, r = lane & 15;

  __shared__ __attribute__((aligned(16))) u16 lA[3*4096];  // 24KB
  __shared__ __attribute__((aligned(16))) u16 lB[3*4096];  // 24KB -> 48KB total

  auto stage = [&](int bi, int k0) {
    u16* dA = lA + bi*4096;
    u16* dB = lB + bi*4096;
#pragma unroll
    for (int i=0;i<2;i++) {
      int ch = wid*2 + i;
      int e = ch*512 + lane*8;
      int row = e >> 5, col = e & 31;
      __builtin_amdgcn_global_load_lds(
        (GLOBAL_AS void*)(A + (size_t)(m0+row)*K + k0 + col),
        (LDS_AS void*)(&dA[ch*512]), 16, 0, 0);
      __builtin_amdgcn_global_load_lds(
        (GLOBAL_AS void*)(Bt + (size_t)(n0+row)*K + k0 + col),
        (LDS_AS void*)(&dB[ch*512]), 16, 0, 0);
    }
  };

  f32x4 acc[4][4];
#pragma unroll
  for (int i=0;i<4;i++)
#pragma unroll
    for (int jj=0;jj<4;jj++) acc[i][jj] = (f32x4){0.f,0.f,0.f,0.f};

  auto compute = [&](int bi, int k0) {
    const u16* sA = lA + bi*4096;
    const u16* sB = lB + bi*4096;
    short8 af[4], bf[4];
#pragma unroll
    for (int f=0; f<4; f++) {
      af[f] = *(const short8*)&sA[(wr*64 + f*16 + r)*32 + g*8];
      bf[f] = *(const short8*)&sB[(wc*64 + f*16 + r)*32 + g*8];
    }
    __builtin_amdgcn_s_setprio(1);
#pragma unroll
    for (int fr=0; fr<4; fr++)
#pragma unroll
      for (int fc=0; fc<4; fc++)
        acc[fr][fc] = __builtin_amdgcn_mfma_f32_16x16x32_bf16(af[fr], bf[fc], acc[fr][fc], 0, 0, 0);
    __builtin_amdgcn_s_setprio(0);
  };

  stage(0, 0);
  stage(1, 32);
  for (int k0 = 0; k0 < K; k0 += 96) {
    asm volatile("s_waitcnt vmcnt(4)" ::: "memory");
    __builtin_amdgcn_s_barrier();
    asm volatile("" ::: "memory");
    stage(2, k0 + 64);
    compute(0, k0);

    asm volatile("s_waitcnt vmcnt(4)" ::: "memory");
    __builtin_amdgcn_s_barrier();
    asm volatile("" ::: "memory");
    { int kn = k0 + 96;  stage(0, kn < K ? kn : 0); }
    compute(1, k0 + 32);

    asm volatile("s_waitcnt vmcnt(4)" ::: "memory");
    __builtin_amdgcn_s_barrier();
    asm volatile("" ::: "memory");
    { int kn = k0 + 128; stage(1, kn < K ? kn : 32); }
    compute(2, k0 + 64);
  }

#pragma unroll
  for (int fr=0; fr<4; fr++)
#pragma unroll
    for (int fc=0; fc<4; fc++)
#pragma unroll
      for (int v=0; v<4; v++) {
        int row = m0 + wr*64 + fr*16 + g*4 + v;
        int cc  = n0 + wc*64 + fc*16 + r;
        outf[(size_t)row*DOUT + cc] = acc[fr][fc][v] + bias[cc];
      }
}

// ---------------- flash attention v9: v8 + setprio + persistent zero C -----
__global__ __launch_bounds__(256, 4) void attn9_k(const u16* __restrict__ Q,
                                                  const u16* __restrict__ Kg,
                                                  const u16* __restrict__ Vt,
                                                  u16* __restrict__ ctx) {
  int i = blockIdx.x;
  int xcd = i & 7, j = i >> 3;         // j in 0..191
  int bh = xcd * 6 + (j >> 5);         // 6 bh per XCD
  int chunk = 31 - (j & 31);           // longest chunks dispatched first
  int nkt = chunk + 1;
  int lane = threadIdx.x & 63;
  int w = threadIdx.x >> 6;
  int p = w >> 1;                      // pair id (q sub-chunk)
  int ch = w & 1;                      // kv half within each tile
  int col = lane & 31;
  int hi = lane >> 5;
  int sw = (col & 7) << 4;             // read-side swizzle

  const u16* Qb = Q  + (size_t)bh * NSEQ * HD;
  const u16* Kb = Kg + (size_t)bh * NSEQ * HD;
  const u16* Vb = Vt + (size_t)bh * HD * NSEQ;

  __shared__ __attribute__((aligned(16))) char smem[2][16384];  // {K,V} x dbuf

  auto stage = [&](int buf, int k0) {
#pragma unroll
    for (int ii=0; ii<2; ii++) {
      int cb = (w*2+ii) * 1024;
      int d  = cb + lane*16;
      int row = d >> 7;
      int src = (d & 127) ^ ((row & 7) << 4);
      __builtin_amdgcn_global_load_lds(
        (GLOBAL_AS void*)((const char*)Kb + (size_t)(k0+row)*128 + src),
        (LDS_AS void*)(&smem[buf][cb]), 16, 0, 0);
      __builtin_amdgcn_global_load_lds(
        (GLOBAL_AS void*)((const char*)Vb + (size_t)row*(NSEQ*2) + (size_t)k0*2 + src),
        (LDS_AS void*)(&smem[buf][8192+cb]), 16, 0, 0);
    }
  };

  int qw0 = chunk*64 + p*32;
  int q = qw0 + col;

  short8 qf[4];
#pragma unroll
  for (int ksl = 0; ksl < 4; ksl++)
    qf[ksl] = *(const short8*)&Qb[(size_t)q * HD + ksl*16 + hi*8];

  short8 ones8;
#pragma unroll
  for (int z=0; z<8; z++) ones8[z] = (short)0x3F80;   // bf16 1.0

  f32x16 od[2], ol, z0;
#pragma unroll
  for (int z=0; z<16; z++) { od[0][z] = 0.f; od[1][z] = 0.f; ol[z] = 0.f; z0[z] = 0.f; }
  asm volatile("" : "+v"(z0));   // keep z0 live as a persistent zero C-operand

  stage(0, 0);

#pragma unroll 1
  for (int t = 0; t < nkt; t++) {
    asm volatile("s_waitcnt vmcnt(0)" ::: "memory");
    __builtin_amdgcn_s_barrier();
    asm volatile("" ::: "memory");

    if (t + 1 < nkt) stage((t+1) & 1, (t+1)*64);

    int k0c = t*64 + ch*32;            // this wave's kv-half base
    if (k0c <= qw0 + 31) {             // wave has live kv in this half
      const char* Kt = &smem[t & 1][0];
      const char* Vtile = &smem[t & 1][8192];
      // ---- QK^T: first ksl uses persistent zero C (no per-tile s init) ----
      short8 kf0 = *(const short8*)(Kt + (ch*32+col)*128 + ((0*32 + hi*16) ^ sw));
      short8 kf1 = *(const short8*)(Kt + (ch*32+col)*128 + ((1*32 + hi*16) ^ sw));
      short8 kf2 = *(const short8*)(Kt + (ch*32+col)*128 + ((2*32 + hi*16) ^ sw));
      short8 kf3 = *(const short8*)(Kt + (ch*32+col)*128 + ((3*32 + hi*16) ^ sw));
      __builtin_amdgcn_s_setprio(1);
      f32x16 s = __builtin_amdgcn_mfma_f32_32x32x16_bf16(kf0, qf[0], z0, 0, 0, 0);
      s = __builtin_amdgcn_mfma_f32_32x32x16_bf16(kf1, qf[1], s, 0, 0, 0);
      s = __builtin_amdgcn_mfma_f32_32x32x16_bf16(kf2, qf[2], s, 0, 0, 0);
      s = __builtin_amdgcn_mfma_f32_32x32x16_bf16(kf3, qf[3], s, 0, 0, 0);
      __builtin_amdgcn_s_setprio(0);
      if (k0c + 31 > qw0) {            // straddles the diagonal: mask
#pragma unroll
        for (int r2=0; r2<16; r2++) {
          int kv = k0c + (r2&3) + 8*(r2>>2) + 4*hi;
          if (kv > q) s[r2] = -1e30f;
        }
      }
      // ---- fixed-base softmax: P = exp2(s), no max tracking ----
      uint32_t a[8];
#pragma unroll
      for (int ww=0; ww<8; ww++) {
        float p0 = __builtin_amdgcn_exp2f(s[2*ww]);
        float p1 = __builtin_amdgcn_exp2f(s[2*ww+1]);
        a[ww] = pack2b(p0, p1);
      }

      // ---- cross-half P^T exchange via permlane32_swap ----
      uint32_t w0=a[0], w2=a[2], w1=a[1], w3=a[3];
      asm volatile("v_permlane32_swap_b32 %0, %1" : "+v"(w0), "+v"(w2));
      asm volatile("v_permlane32_swap_b32 %0, %1" : "+v"(w1), "+v"(w3));
      uint32_t w4=a[4], w6=a[6], w5=a[5], w7=a[7];
      asm volatile("v_permlane32_swap_b32 %0, %1" : "+v"(w4), "+v"(w6));
      asm volatile("v_permlane32_swap_b32 %0, %1" : "+v"(w5), "+v"(w7));
      union { uint32_t wdat[4]; short8 s8; } u0, u1;
      u0.wdat[0]=w0; u0.wdat[1]=w1; u0.wdat[2]=w2; u0.wdat[3]=w3;
      u1.wdat[0]=w4; u1.wdat[1]=w5; u1.wdat[2]=w6; u1.wdat[3]=w7;

      // ---- PV: O^T += Vt_half * P^T_half (K=32); l via ones-MFMA ----
      short8 vf00 = *(const short8*)(Vtile + (0*32+col)*128 + ((ch*64 + hi*16) ^ sw));
      short8 vf01 = *(const short8*)(Vtile + (0*32+col)*128 + ((ch*64 + 32 + hi*16) ^ sw));
      short8 vf10 = *(const short8*)(Vtile + (1*32+col)*128 + ((ch*64 + hi*16) ^ sw));
      short8 vf11 = *(const short8*)(Vtile + (1*32+col)*128 + ((ch*64 + 32 + hi*16) ^ sw));
      __builtin_amdgcn_s_setprio(1);
      od[0] = __builtin_amdgcn_mfma_f32_32x32x16_bf16(vf00, u0.s8, od[0], 0, 0, 0);
      od[0] = __builtin_amdgcn_mfma_f32_32x32x16_bf16(vf01, u1.s8, od[0], 0, 0, 0);
      od[1] = __builtin_amdgcn_mfma_f32_32x32x16_bf16(vf10, u0.s8, od[1], 0, 0, 0);
      od[1] = __builtin_amdgcn_mfma_f32_32x32x16_bf16(vf11, u1.s8, od[1], 0, 0, 0);
      ol = __builtin_amdgcn_mfma_f32_32x32x16_bf16(ones8, u0.s8, ol, 0, 0, 0);
      ol = __builtin_amdgcn_mfma_f32_32x32x16_bf16(ones8, u1.s8, ol, 0, 0, 0);
      __builtin_amdgcn_s_setprio(0);
    }
  }
  __syncthreads();   // all compute done before merge overwrites smem

  // ---- pair merge through LDS: O = (odA+odB) / (lA+lB) ----
  float* mg = (float*)&smem[0][0] + p * (33*64);
  if (ch) {
#pragma unroll
    for (int dc=0; dc<2; dc++)
#pragma unroll
      for (int jj=0; jj<16; jj++) mg[(dc*16+jj)*64 + lane] = od[dc][jj];
    mg[32*64 + lane] = ol[0];
  }
  __syncthreads();
  if (!ch) {
    float inv = 1.0f / (ol[0] + mg[32*64 + lane]);
    int b = bh / NH, h = bh % NH;
    u16* cp_ = ctx + ((size_t)b * NSEQ + q) * DOUT + h * HD;
#pragma unroll
    for (int dc=0; dc<2; dc++)
#pragma unroll
      for (int t4=0; t4<4; t4++) {
        int d0 = dc*32 + t4*8 + hi*4;
        float v0 = (od[dc][t4*4+0] + mg[(dc*16+t4*4+0)*64 + lane]) * inv;
        float v1 = (od[dc][t4*4+1] + mg[(dc*16+t4*4+1)*64 + lane]) * inv;
        float v2 = (od[dc][t4*4+2] + mg[(dc*16+t4*4+2)*64 + lane]) * inv;
        float v3 = (od[dc][t4*4+3] + mg[(dc*16+t4*4+3)*64 + lane]) * inv;
        *(uint32_t*)(cp_ + d0)     = pack2b(v0, v1);
        *(uint32_t*)(cp_ + d0 + 2) = pack2b(v2, v3);
      }
  }
}

// ---------------------------------------------------------------------------
extern "C" void kernel_launch(void* const* d_in, const int* in_sizes, int n_in,
                              void* d_out, int out_size, void* d_ws, size_t ws_size,
                              hipStream_t stream) {
  const float* x   = (const float*)d_in[0];
  const float* Wq  = (const float*)d_in[1];
  const float* Wk  = (const float*)d_in[2];
  const float* Wv  = (const float*)d_in[3];
  const float* Wo  = (const float*)d_in[4];
  const float* bo  = (const float*)d_in[5];
  float* out = (float*)d_out;

  u16* ws  = (u16*)d_ws;
  u16* xb  = ws;                         // [8192][768]
  u16* WqT = xb  + (size_t)MROWS*DIN;    // [768][768] transposed   }
  u16* WkT = WqT + (size_t)DIN*DOUT;     //                         } contiguous [2304][768]
  u16* WvT = WkT + (size_t)DIN*DOUT;     //                         }
  u16* WoT = WvT + (size_t)DIN*DOUT;
  u16* Qg  = WoT + (size_t)DIN*DOUT;     // [b][h][n][64]  (pre-scaled)
  u16* Kg  = Qg  + (size_t)MROWS*DOUT;   // [b][h][n][64]
  u16* Vt  = Kg  + (size_t)MROWS*DOUT;   // [b][h][64][n]
  u16* ctx = Vt  + (size_t)MROWS*DOUT;   // [b][n][768]

  convert2_k<<<2624, 256, 0, stream>>>(x, Wq, Wk, Wv, Wo, xb, WqT, WkT, WvT, WoT);

  gemm_qkv_k<<<1152, 256, 0, stream>>>(xb, WqT, Qg, Kg, Vt);

  attn9_k<<<1536, 256, 0, stream>>>(Qg, Kg, Vt, ctx);

  gemm_o_k<<<384, 256, 0, stream>>>(ctx, WoT, out, bo);
}

// Round 18
// 126.885 us; speedup vs baseline: 1.3859x; 1.3859x over previous
//
#include <hip/hip_runtime.h>
#include <hip/hip_bf16.h>
#include <stdint.h>

typedef unsigned short u16;
typedef __attribute__((ext_vector_type(8))) short short8;
typedef __attribute__((ext_vector_type(4))) float f32x4;
typedef __attribute__((ext_vector_type(16))) float f32x16;

#define GLOBAL_AS __attribute__((address_space(1)))
#define LDS_AS __attribute__((address_space(3)))

#define BB 4
#define NSEQ 2048
#define DIN 768
#define DOUT 768
#define NH 12
#define HD 64
#define MROWS (BB*NSEQ)   // 8192

static __device__ __forceinline__ u16 f2bf(float f) {
  union { float f; uint32_t u; } v; v.f = f;
  uint32_t r = (v.u + 0x7fffu + ((v.u >> 16) & 1u)) >> 16;
  return (u16)r;
}
static __device__ __forceinline__ uint32_t pack2b(float lo, float hi) {
  union { __hip_bfloat162 h; uint32_t u; } cv;
  cv.h.x = __float2bfloat16(lo);
  cv.h.y = __float2bfloat16(hi);
  return cv.u;
}

// ---------------- convert v2 ------------------------------------------------
__global__ __launch_bounds__(256) void convert2_k(const float* __restrict__ x,
                          const float* __restrict__ Wq, const float* __restrict__ Wk,
                          const float* __restrict__ Wv, const float* __restrict__ Wo,
                          u16* __restrict__ xb, u16* __restrict__ WqT,
                          u16* __restrict__ WkT, u16* __restrict__ WvT,
                          u16* __restrict__ WoT) {
  int tid = threadIdx.x;
  if (blockIdx.x < 576) {
    int wi = blockIdx.x;
    int which = wi / 144, t = wi % 144;
    int tr = t / 12, tc = t % 12;          // k-tile, n-tile
    const float* src = which==0 ? Wq : which==1 ? Wk : which==2 ? Wv : Wo;
    u16* dst = which==0 ? WqT : which==1 ? WkT : which==2 ? WvT : WoT;
    __shared__ u16 lt[64][65];
    int r0 = tid >> 6, c = tid & 63;
#pragma unroll
    for (int rr=0; rr<16; rr++) {
      int row = rr*4 + r0;                 // k within tile
      lt[row][c] = f2bf(src[(size_t)(tr*64+row)*DOUT + tc*64 + c]);
    }
    __syncthreads();
#pragma unroll
    for (int rr=0; rr<16; rr++) {
      int row = rr*4 + r0;                 // n within tile
      dst[(size_t)(tc*64+row)*DIN + tr*64 + c] = lt[c][row];
    }
  } else {
    const float4* x4 = (const float4*)x;
    uint2* o4 = (uint2*)xb;
    int n4 = MROWS*DIN/4;                  // 1572864
    int i = (int)(blockIdx.x - 576) * 256 + tid;
    for (; i < n4; i += 2048*256) {
      float4 v = x4[i];
      uint2 o; o.x = pack2b(v.x, v.y); o.y = pack2b(v.z, v.w);
      o4[i] = o;
    }
  }
}

// ---------------- fused QKV GEMM v4b: 3-buffer counted-vmcnt pipeline ------
// (round-15 verbatim; round-17's setprio-only variant exposed a flaky
// timing-sensitive divergence on graph replay, so T5 is dropped.)
__global__ __launch_bounds__(256) void gemm_qkv_k(const u16* __restrict__ A,
                                                  const u16* __restrict__ Bt,
                                                  u16* __restrict__ Qg,
                                                  u16* __restrict__ Kgo,
                                                  u16* __restrict__ Vto) {
  const int K = DIN;
  int xcd = blockIdx.x & 7, j = blockIdx.x >> 3;   // j 0..143
  int m0 = (xcd*8 + (j & 7)) * 128;
  int nt = j >> 3;                                 // 0..17
  nt = (nt % 3) * 6 + nt / 3;                      // spread V^T columns
  int n0 = nt * 128;
  int tid = threadIdx.x;
  int lane = tid & 63, wid = tid >> 6;
  int wr = wid >> 1, wc = wid & 1;
  int g = lane >> 4, r = lane & 15;

  __shared__ __attribute__((aligned(16))) u16 sbuf[24576];  // 48KB
  // A bufs @ 0/4096/8192 ; B bufs @ 12288/16384/20480 (elements)

  auto stage = [&](int bi, int k0) {
    u16* dA = sbuf + bi*4096;
    u16* dB = sbuf + 12288 + bi*4096;
#pragma unroll
    for (int i=0;i<2;i++) {
      int ch = wid*2 + i;
      int e = ch*512 + lane*8;
      int row = e >> 5, col = e & 31;
      __builtin_amdgcn_global_load_lds(
        (GLOBAL_AS void*)(A + (size_t)(m0+row)*K + k0 + col),
        (LDS_AS void*)(&dA[ch*512]), 16, 0, 0);
      __builtin_amdgcn_global_load_lds(
        (GLOBAL_AS void*)(Bt + (size_t)(n0+row)*K + k0 + col),
        (LDS_AS void*)(&dB[ch*512]), 16, 0, 0);
    }
  };

  f32x4 acc[4][4];
#pragma unroll
  for (int i=0;i<4;i++)
#pragma unroll
    for (int jj=0;jj<4;jj++) acc[i][jj] = (f32x4){0.f,0.f,0.f,0.f};

  auto compute = [&](int bi, int k0) {
    const u16* sA = sbuf + bi*4096;
    const u16* sB = sbuf + 12288 + bi*4096;
    short8 af[4], bf[4];
#pragma unroll
    for (int f=0; f<4; f++) {
      af[f] = *(const short8*)&sA[(wr*64 + f*16 + r)*32 + g*8];
      bf[f] = *(const short8*)&sB[(wc*64 + f*16 + r)*32 + g*8];
    }
#pragma unroll
    for (int fr=0; fr<4; fr++)
#pragma unroll
      for (int fc=0; fc<4; fc++)
        acc[fr][fc] = __builtin_amdgcn_mfma_f32_16x16x32_bf16(af[fr], bf[fc], acc[fr][fc], 0, 0, 0);
  };

  stage(0, 0);
  stage(1, 32);
  for (int k0 = 0; k0 < K; k0 += 96) {
    asm volatile("s_waitcnt vmcnt(4)" ::: "memory");
    __builtin_amdgcn_s_barrier();
    asm volatile("" ::: "memory");
    stage(2, k0 + 64);
    compute(0, k0);

    asm volatile("s_waitcnt vmcnt(4)" ::: "memory");
    __builtin_amdgcn_s_barrier();
    asm volatile("" ::: "memory");
    { int kn = k0 + 96;  stage(0, kn < K ? kn : 0); }
    compute(1, k0 + 32);

    asm volatile("s_waitcnt vmcnt(4)" ::: "memory");
    __builtin_amdgcn_s_barrier();
    asm volatile("" ::: "memory");
    { int kn = k0 + 128; stage(1, kn < K ? kn : 32); }
    compute(2, k0 + 64);
  }
  asm volatile("s_waitcnt vmcnt(0)" ::: "memory");
  __syncthreads();   // all loads landed + all compute done before epilogue reuse

  if (n0 < 1536) {                   // Q or K path
    bool isQ = n0 < 768;
    u16* outb = isQ ? Qg : Kgo;
    int nb = isQ ? n0 : n0 - 768;
#pragma unroll
    for (int fr=0; fr<4; fr++)
#pragma unroll
      for (int fc=0; fc<4; fc++)
#pragma unroll
        for (int v=0; v<4; v++) {
          int row = m0 + wr*64 + fr*16 + g*4 + v;
          int cc  = nb + wc*64 + fc*16 + r;
          int b = row >> 11, nn = row & (NSEQ-1);
          float val = acc[fr][fc][v];
          if (isQ) val *= 0.18033688f;   // 0.125 * log2(e)
          outb[(((size_t)b*NH + (cc>>6))*NSEQ + nn)*HD + (cc&63)] = f2bf(val);
        }
  } else {                           // V^T path: single-shot LDS transpose
    int nb = n0 - 1536;
#pragma unroll
    for (int fr=0; fr<4; fr++)
#pragma unroll
      for (int fc=0; fc<4; fc++)
#pragma unroll
        for (int v=0; v<4; v++) {
          int ii = wr*64 + fr*16 + g*4 + v;
          int jj = wc*64 + fc*16 + r;
          sbuf[ii*129 + jj] = f2bf(acc[fr][fc][v]);
        }
    __syncthreads();
    int b = m0 >> 11;
#pragma unroll 1
    for (int rep=0; rep<64; rep++) {
      int flat = rep*256 + tid;      // 16384 elements
      int jj = flat >> 7, ii = flat & 127;
      int cc = nb + jj;
      int nn = (m0 + ii) & (NSEQ-1);
      Vto[(((size_t)b*NH + (cc>>6))*HD + (cc&63))*NSEQ + nn] = sbuf[ii*129 + jj];
    }
  }
}

// ---------------- final GEMM v4b: 3-buffer counted-vmcnt pipeline ----------
__global__ __launch_bounds__(256) void gemm_o_k(const u16* __restrict__ A,
                                                const u16* __restrict__ Bt,
                                                float* __restrict__ outf,
                                                const float* __restrict__ bias) {
  const int K = DIN;
  int xcd = blockIdx.x & 7, j = blockIdx.x >> 3;   // j 0..47
  int m0 = (xcd*8 + (j & 7)) * 128;
  int n0 = (j >> 3) * 128;                         // 0..5
  int tid = threadIdx.x;
  int lane = tid & 63, wid = tid >> 6;
  int wr = wid >> 1, wc = wid & 1;
  int g = lane >> 4, r = lane & 15;

  __shared__ __attribute__((aligned(16))) u16 lA[3*4096];  // 24KB
  __shared__ __attribute__((aligned(16))) u16 lB[3*4096];  // 24KB -> 48KB total

  auto stage = [&](int bi, int k0) {
    u16* dA = lA + bi*4096;
    u16* dB = lB + bi*4096;
#pragma unroll
    for (int i=0;i<2;i++) {
      int ch = wid*2 + i;
      int e = ch*512 + lane*8;
      int row = e >> 5, col = e & 31;
      __builtin_amdgcn_global_load_lds(
        (GLOBAL_AS void*)(A + (size_t)(m0+row)*K + k0 + col),
        (LDS_AS void*)(&dA[ch*512]), 16, 0, 0);
      __builtin_amdgcn_global_load_lds(
        (GLOBAL_AS void*)(Bt + (size_t)(n0+row)*K + k0 + col),
        (LDS_AS void*)(&dB[ch*512]), 16, 0, 0);
    }
  };

  f32x4 acc[4][4];
#pragma unroll
  for (int i=0;i<4;i++)
#pragma unroll
    for (int jj=0;jj<4;jj++) acc[i][jj] = (f32x4){0.f,0.f,0.f,0.f};

  auto compute = [&](int bi, int k0) {
    const u16* sA = lA + bi*4096;
    const u16* sB = lB + bi*4096;
    short8 af[4], bf[4];
#pragma unroll
    for (int f=0; f<4; f++) {
      af[f] = *(const short8*)&sA[(wr*64 + f*16 + r)*32 + g*8];
      bf[f] = *(const short8*)&sB[(wc*64 + f*16 + r)*32 + g*8];
    }
#pragma unroll
    for (int fr=0; fr<4; fr++)
#pragma unroll
      for (int fc=0; fc<4; fc++)
        acc[fr][fc] = __builtin_amdgcn_mfma_f32_16x16x32_bf16(af[fr], bf[fc], acc[fr][fc], 0, 0, 0);
  };

  stage(0, 0);
  stage(1, 32);
  for (int k0 = 0; k0 < K; k0 += 96) {
    asm volatile("s_waitcnt vmcnt(4)" ::: "memory");
    __builtin_amdgcn_s_barrier();
    asm volatile("" ::: "memory");
    stage(2, k0 + 64);
    compute(0, k0);

    asm volatile("s_waitcnt vmcnt(4)" ::: "memory");
    __builtin_amdgcn_s_barrier();
    asm volatile("" ::: "memory");
    { int kn = k0 + 96;  stage(0, kn < K ? kn : 0); }
    compute(1, k0 + 32);

    asm volatile("s_waitcnt vmcnt(4)" ::: "memory");
    __builtin_amdgcn_s_barrier();
    asm volatile("" ::: "memory");
    { int kn = k0 + 128; stage(1, kn < K ? kn : 32); }
    compute(2, k0 + 64);
  }

#pragma unroll
  for (int fr=0; fr<4; fr++)
#pragma unroll
    for (int fc=0; fc<4; fc++)
#pragma unroll
      for (int v=0; v<4; v++) {
        int row = m0 + wr*64 + fr*16 + g*4 + v;
        int cc  = n0 + wc*64 + fc*16 + r;
        outf[(size_t)row*DOUT + cc] = acc[fr][fc][v] + bias[cc];
      }
}

// ---------------- flash attention v8 (round-15 verbatim, no setprio) -------
__global__ __launch_bounds__(256, 4) void attn8_k(const u16* __restrict__ Q,
                                                  const u16* __restrict__ Kg,
                                                  const u16* __restrict__ Vt,
                                                  u16* __restrict__ ctx) {
  int i = blockIdx.x;
  int xcd = i & 7, j = i >> 3;         // j in 0..191
  int bh = xcd * 6 + (j >> 5);         // 6 bh per XCD
  int chunk = 31 - (j & 31);           // longest chunks dispatched first
  int nkt = chunk + 1;
  int lane = threadIdx.x & 63;
  int w = threadIdx.x >> 6;
  int p = w >> 1;                      // pair id (q sub-chunk)
  int ch = w & 1;                      // kv half within each tile
  int col = lane & 31;
  int hi = lane >> 5;
  int sw = (col & 7) << 4;             // read-side swizzle

  const u16* Qb = Q  + (size_t)bh * NSEQ * HD;
  const u16* Kb = Kg + (size_t)bh * NSEQ * HD;
  const u16* Vb = Vt + (size_t)bh * HD * NSEQ;

  __shared__ __attribute__((aligned(16))) char smem[2][16384];  // {K,V} x dbuf

  auto stage = [&](int buf, int k0) {
#pragma unroll
    for (int ii=0; ii<2; ii++) {
      int cb = (w*2+ii) * 1024;
      int d  = cb + lane*16;
      int row = d >> 7;
      int src = (d & 127) ^ ((row & 7) << 4);
      __builtin_amdgcn_global_load_lds(
        (GLOBAL_AS void*)((const char*)Kb + (size_t)(k0+row)*128 + src),
        (LDS_AS void*)(&smem[buf][cb]), 16, 0, 0);
      __builtin_amdgcn_global_load_lds(
        (GLOBAL_AS void*)((const char*)Vb + (size_t)row*(NSEQ*2) + (size_t)k0*2 + src),
        (LDS_AS void*)(&smem[buf][8192+cb]), 16, 0, 0);
    }
  };

  int qw0 = chunk*64 + p*32;
  int q = qw0 + col;

  short8 qf[4];
#pragma unroll
  for (int ksl = 0; ksl < 4; ksl++)
    qf[ksl] = *(const short8*)&Qb[(size_t)q * HD + ksl*16 + hi*8];

  short8 ones8;
#pragma unroll
  for (int z=0; z<8; z++) ones8[z] = (short)0x3F80;   // bf16 1.0

  f32x16 od[2], ol;
#pragma unroll
  for (int z=0; z<16; z++) { od[0][z] = 0.f; od[1][z] = 0.f; ol[z] = 0.f; }

  stage(0, 0);

#pragma unroll 1
  for (int t = 0; t < nkt; t++) {
    asm volatile("s_waitcnt vmcnt(0)" ::: "memory");
    __builtin_amdgcn_s_barrier();
    asm volatile("" ::: "memory");

    if (t + 1 < nkt) stage((t+1) & 1, (t+1)*64);

    int k0c = t*64 + ch*32;            // this wave's kv-half base
    if (k0c <= qw0 + 31) {             // wave has live kv in this half
      const char* Kt = &smem[t & 1][0];
      const char* Vtile = &smem[t & 1][8192];
      f32x16 s;
#pragma unroll
      for (int z=0; z<16; z++) s[z] = 0.f;
#pragma unroll
      for (int ksl=0; ksl<4; ksl++) {
        short8 kf = *(const short8*)(Kt + (ch*32+col)*128 + ((ksl*32 + hi*16) ^ sw));
        s = __builtin_amdgcn_mfma_f32_32x32x16_bf16(kf, qf[ksl], s, 0, 0, 0);
      }
      if (k0c + 31 > qw0) {            // straddles the diagonal: mask
#pragma unroll
        for (int r2=0; r2<16; r2++) {
          int kv = k0c + (r2&3) + 8*(r2>>2) + 4*hi;
          if (kv > q) s[r2] = -1e30f;
        }
      }
      // ---- fixed-base softmax: P = exp2(s), no max tracking ----
      uint32_t a[8];
#pragma unroll
      for (int ww=0; ww<8; ww++) {
        float p0 = __builtin_amdgcn_exp2f(s[2*ww]);
        float p1 = __builtin_amdgcn_exp2f(s[2*ww+1]);
        a[ww] = pack2b(p0, p1);
      }

      // ---- cross-half P^T exchange via permlane32_swap ----
      uint32_t w0=a[0], w2=a[2], w1=a[1], w3=a[3];
      asm volatile("v_permlane32_swap_b32 %0, %1" : "+v"(w0), "+v"(w2));
      asm volatile("v_permlane32_swap_b32 %0, %1" : "+v"(w1), "+v"(w3));
      uint32_t w4=a[4], w6=a[6], w5=a[5], w7=a[7];
      asm volatile("v_permlane32_swap_b32 %0, %1" : "+v"(w4), "+v"(w6));
      asm volatile("v_permlane32_swap_b32 %0, %1" : "+v"(w5), "+v"(w7));
      union { uint32_t wdat[4]; short8 s8; } u0, u1;
      u0.wdat[0]=w0; u0.wdat[1]=w1; u0.wdat[2]=w2; u0.wdat[3]=w3;
      u1.wdat[0]=w4; u1.wdat[1]=w5; u1.wdat[2]=w6; u1.wdat[3]=w7;

      // ---- PV: O^T += Vt_half * P^T_half (K=32); l via ones-MFMA ----
#pragma unroll
      for (int dc=0; dc<2; dc++) {
        short8 vf0 = *(const short8*)(Vtile + (dc*32+col)*128 + ((ch*64 + hi*16) ^ sw));
        od[dc] = __builtin_amdgcn_mfma_f32_32x32x16_bf16(vf0, u0.s8, od[dc], 0, 0, 0);
        short8 vf1 = *(const short8*)(Vtile + (dc*32+col)*128 + ((ch*64 + 32 + hi*16) ^ sw));
        od[dc] = __builtin_amdgcn_mfma_f32_32x32x16_bf16(vf1, u1.s8, od[dc], 0, 0, 0);
      }
      ol = __builtin_amdgcn_mfma_f32_32x32x16_bf16(ones8, u0.s8, ol, 0, 0, 0);
      ol = __builtin_amdgcn_mfma_f32_32x32x16_bf16(ones8, u1.s8, ol, 0, 0, 0);
    }
  }
  __syncthreads();   // all compute done before merge overwrites smem

  // ---- pair merge through LDS: O = (odA+odB) / (lA+lB) ----
  float* mg = (float*)&smem[0][0] + p * (33*64);
  if (ch) {
#pragma unroll
    for (int dc=0; dc<2; dc++)
#pragma unroll
      for (int jj=0; jj<16; jj++) mg[(dc*16+jj)*64 + lane] = od[dc][jj];
    mg[32*64 + lane] = ol[0];
  }
  __syncthreads();
  if (!ch) {
    float inv = 1.0f / (ol[0] + mg[32*64 + lane]);
    int b = bh / NH, h = bh % NH;
    u16* cp_ = ctx + ((size_t)b * NSEQ + q) * DOUT + h * HD;
#pragma unroll
    for (int dc=0; dc<2; dc++)
#pragma unroll
      for (int t4=0; t4<4; t4++) {
        int d0 = dc*32 + t4*8 + hi*4;
        float v0 = (od[dc][t4*4+0] + mg[(dc*16+t4*4+0)*64 + lane]) * inv;
        float v1 = (od[dc][t4*4+1] + mg[(dc*16+t4*4+1)*64 + lane]) * inv;
        float v2 = (od[dc][t4*4+2] + mg[(dc*16+t4*4+2)*64 + lane]) * inv;
        float v3 = (od[dc][t4*4+3] + mg[(dc*16+t4*4+3)*64 + lane]) * inv;
        *(uint32_t*)(cp_ + d0)     = pack2b(v0, v1);
        *(uint32_t*)(cp_ + d0 + 2) = pack2b(v2, v3);
      }
  }
}

// ---------------------------------------------------------------------------
extern "C" void kernel_launch(void* const* d_in, const int* in_sizes, int n_in,
                              void* d_out, int out_size, void* d_ws, size_t ws_size,
                              hipStream_t stream) {
  const float* x   = (const float*)d_in[0];
  const float* Wq  = (const float*)d_in[1];
  const float* Wk  = (const float*)d_in[2];
  const float* Wv  = (const float*)d_in[3];
  const float* Wo  = (const float*)d_in[4];
  const float* bo  = (const float*)d_in[5];
  float* out = (float*)d_out;

  u16* ws  = (u16*)d_ws;
  u16* xb  = ws;                         // [8192][768]
  u16* WqT = xb  + (size_t)MROWS*DIN;    // [768][768] transposed   }
  u16* WkT = WqT + (size_t)DIN*DOUT;     //                         } contiguous [2304][768]
  u16* WvT = WkT + (size_t)DIN*DOUT;     //                         }
  u16* WoT = WvT + (size_t)DIN*DOUT;
  u16* Qg  = WoT + (size_t)DIN*DOUT;     // [b][h][n][64]  (pre-scaled)
  u16* Kg  = Qg  + (size_t)MROWS*DOUT;   // [b][h][n][64]
  u16* Vt  = Kg  + (size_t)MROWS*DOUT;   // [b][h][64][n]
  u16* ctx = Vt  + (size_t)MROWS*DOUT;   // [b][n][768]

  convert2_k<<<2624, 256, 0, stream>>>(x, Wq, Wk, Wv, Wo, xb, WqT, WkT, WvT, WoT);

  gemm_qkv_k<<<1152, 256, 0, stream>>>(xb, WqT, Qg, Kg, Vt);

  attn8_k<<<1536, 256, 0, stream>>>(Qg, Kg, Vt, ctx);

  gemm_o_k<<<384, 256, 0, stream>>>(ctx, WoT, out, bo);
}